// Round 3
// baseline (1403.135 us; speedup 1.0000x reference)
//
#include <hip/hip_runtime.h>
#include <cstdint>
#include <cstddef>

#define NNODES 50000
#define DIM 128
#define K5 640          // 5*DIM
#define OUTD 128
#define MPAD 50048      // NNODES rounded up to multiple of 64
#define NBLK 782        // MPAD/64
#define EPS_STD 1e-5f
#define EPS_BN 1e-5f
#define LDA 40          // padded LDS leading dim per 32-k chunk (proven in r1/r2 gemm)

typedef __attribute__((ext_vector_type(8))) __bf16 bf16x8;
typedef __attribute__((ext_vector_type(4))) float f32x4;

__device__ __forceinline__ unsigned short f2bf(float f) {
  unsigned int u = __float_as_uint(f);
  u = u + 0x7fffu + ((u >> 16) & 1u);
  return (unsigned short)(u >> 16);
}

// ---------------- histogram ----------------
__global__ void hist_k(const int* __restrict__ idx, int* __restrict__ counts, int E) {
  int e = blockIdx.x * 256 + threadIdx.x;
  if (e < E) atomicAdd(&counts[idx[e]], 1);
}

// ---------------- 2-level exclusive scan ----------------
__global__ void scan1_k(const int* __restrict__ counts, int* __restrict__ offsets,
                        int* __restrict__ blocksums, int n) {
  __shared__ int sh[256];
  int t = threadIdx.x;
  int i = blockIdx.x * 256 + t;
  int v = (i < n) ? counts[i] : 0;
  sh[t] = v; __syncthreads();
  for (int off = 1; off < 256; off <<= 1) {
    int add = (t >= off) ? sh[t - off] : 0;
    __syncthreads();
    sh[t] += add;
    __syncthreads();
  }
  if (i < n) offsets[i] = sh[t] - v;   // exclusive
  if (t == 255) blocksums[blockIdx.x] = sh[t];
}

__global__ void scan2_k(int* __restrict__ blocksums, int nb) {
  __shared__ int sh[256];
  int t = threadIdx.x;
  int v = (t < nb) ? blocksums[t] : 0;
  sh[t] = v; __syncthreads();
  for (int off = 1; off < 256; off <<= 1) {
    int add = (t >= off) ? sh[t - off] : 0;
    __syncthreads();
    sh[t] += add;
    __syncthreads();
  }
  if (t < nb) blocksums[t] = sh[t] - v; // exclusive
}

__global__ void scan3_k(int* __restrict__ offsets, const int* __restrict__ blocksums,
                        int* __restrict__ cursor, int n) {
  int i = blockIdx.x * 256 + threadIdx.x;
  if (i < n) {
    int o = offsets[i] + blocksums[blockIdx.x];
    offsets[i] = o;
    cursor[i] = o;
  }
}

// ---------------- scatter: counting sort of edge ids ----------------
__global__ void scatter_k(const int* __restrict__ idx, int* __restrict__ cursor,
                          int* __restrict__ sorted, int E) {
  int e = blockIdx.x * 256 + threadIdx.x;
  if (e < E) {
    int p = atomicAdd(&cursor[idx[e]], 1);
    sorted[p] = e;
  }
}

// ---------------- W (fp32 [K5,OUTD]) -> Wt bf16 col-major [OUTD][K5] ----------------
__global__ void convW_k(const float* __restrict__ W, unsigned short* __restrict__ Wt) {
  int t = blockIdx.x * 256 + threadIdx.x;
  if (t >= OUTD * K5) return;
  int c = t / K5, k = t % K5;
  Wt[t] = f2bf(W[(size_t)k * OUTD + c]);
}

// ---------------- FUSED: aggregate (64 nodes -> LDS bf16) + MFMA GEMM + BN stats ----
__global__ __launch_bounds__(512, 1) void fused_k(
    const float* __restrict__ inp, const int* __restrict__ sorted,
    const int* __restrict__ offsets, const int* __restrict__ counts,
    const float* __restrict__ deg_emb, const unsigned short* __restrict__ Wt,
    float* __restrict__ h, float* __restrict__ colsum, float* __restrict__ colsumsq) {
  // As[c][row][kk]: 20 chunks of 32 k, 64 rows, padded to 40 shorts
  __shared__ unsigned short As[20 * 64 * LDA];   // 102400 B
  __shared__ float sh_s[8 * 64];
  __shared__ float sh_q[8 * 64];

  const int t    = threadIdx.x;
  const int wv   = t >> 6;         // wave 0..7
  const int lane = t & 63;
  const int m0   = blockIdx.x * 64;

  // ---------------- phase 1: aggregation, 8 nodes per wave ----------------
  {
    const int half = lane >> 5;    // 0: even rows, 1: odd rows of the edge batch
    const int sl   = lane & 31;
    const int c0   = sl * 4;       // 4 feature columns per lane
    // LDS write mapping for k = sgm*128 + sl*4
    const int wc   = sl >> 3;          // chunk sub-index within segment
    const int wkk  = (sl & 7) * 4;     // k offset within chunk

    for (int i = 0; i < 8; i++) {
      const int r    = wv * 8 + i;     // local row 0..63
      const int node = m0 + r;

      if (node >= NNODES) {            // pad row -> zeros
        if (half == 0) {
          ushort4 z = {0, 0, 0, 0};
          #pragma unroll
          for (int sgm = 0; sgm < 5; sgm++) {
            const int c = sgm * 4 + wc;
            *(ushort4*)&As[(c * 64 + r) * LDA + wkk] = z;
          }
        }
        continue;
      }

      const int start = offsets[node];
      const int cnt   = counts[node];
      float s[4] = {0.f, 0.f, 0.f, 0.f}, q[4] = {0.f, 0.f, 0.f, 0.f};
      float mn[4], mx[4];
      #pragma unroll
      for (int k = 0; k < 4; k++) { mn[k] = INFINITY; mx[k] = -INFINITY; }

      for (int j0 = 0; j0 < cnt; j0 += 64) {
        const int lim = min(64, cnt - j0);
        int myid = 0;
        if (j0 + lane < cnt) myid = sorted[start + j0 + lane];
        int j = 0;
        for (; j + 8 <= lim; j += 8) {   // 4 independent gathers in flight
          const int e0 = __shfl(myid, j + 0 + half);
          const int e1 = __shfl(myid, j + 2 + half);
          const int e2 = __shfl(myid, j + 4 + half);
          const int e3 = __shfl(myid, j + 6 + half);
          const float4 a0 = *(const float4*)(inp + (size_t)e0 * DIM + c0);
          const float4 a1 = *(const float4*)(inp + (size_t)e1 * DIM + c0);
          const float4 a2 = *(const float4*)(inp + (size_t)e2 * DIM + c0);
          const float4 a3 = *(const float4*)(inp + (size_t)e3 * DIM + c0);
          const float v0[4] = {a0.x, a0.y, a0.z, a0.w};
          const float v1[4] = {a1.x, a1.y, a1.z, a1.w};
          const float v2[4] = {a2.x, a2.y, a2.z, a2.w};
          const float v3[4] = {a3.x, a3.y, a3.z, a3.w};
          #pragma unroll
          for (int k = 0; k < 4; k++) {
            s[k] += v0[k] + v1[k] + v2[k] + v3[k];
            q[k] += v0[k] * v0[k] + v1[k] * v1[k] + v2[k] * v2[k] + v3[k] * v3[k];
            mn[k] = fminf(fminf(fminf(mn[k], v0[k]), fminf(v1[k], v2[k])), v3[k]);
            mx[k] = fmaxf(fmaxf(fmaxf(mx[k], v0[k]), fmaxf(v1[k], v2[k])), v3[k]);
          }
        }
        for (; j < lim; j += 2) {        // tail
          const int rr = j + half;
          const int e = __shfl(myid, rr < lim ? rr : (lim - 1));
          if (rr < lim) {
            const float4 a = *(const float4*)(inp + (size_t)e * DIM + c0);
            const float v[4] = {a.x, a.y, a.z, a.w};
            #pragma unroll
            for (int k = 0; k < 4; k++) {
              s[k] += v[k];
              q[k] += v[k] * v[k];
              mn[k] = fminf(mn[k], v[k]);
              mx[k] = fmaxf(mx[k], v[k]);
            }
          }
        }
      }
      // combine the two half-wave row groups
      #pragma unroll
      for (int k = 0; k < 4; k++) {
        s[k] += __shfl_xor(s[k], 32);
        q[k] += __shfl_xor(q[k], 32);
        mn[k] = fminf(mn[k], __shfl_xor(mn[k], 32));
        mx[k] = fmaxf(mx[k], __shfl_xor(mx[k], 32));
      }

      if (half == 0) {
        const float inv = 1.0f / (float)max(cnt, 1);
        const int deg = min(cnt, 99);
        const float4 e4 = *(const float4*)(deg_emb + (size_t)deg * DIM + c0);
        const float emb[4] = {e4.x, e4.y, e4.z, e4.w};
        float mean[4], sd[4];
        #pragma unroll
        for (int k = 0; k < 4; k++) {
          mean[k] = s[k] * inv;
          float var = q[k] * inv - mean[k] * mean[k];
          sd[k] = sqrtf(fmaxf(var, 0.f) + EPS_STD);
          if (cnt == 0) { mn[k] = 0.f; mx[k] = 0.f; }
        }
        const ushort4 seg[5] = {
          {f2bf(mean[0]), f2bf(mean[1]), f2bf(mean[2]), f2bf(mean[3])},
          {f2bf(mn[0]),   f2bf(mn[1]),   f2bf(mn[2]),   f2bf(mn[3])},
          {f2bf(mx[0]),   f2bf(mx[1]),   f2bf(mx[2]),   f2bf(mx[3])},
          {f2bf(sd[0]),   f2bf(sd[1]),   f2bf(sd[2]),   f2bf(sd[3])},
          {f2bf(emb[0]),  f2bf(emb[1]),  f2bf(emb[2]),  f2bf(emb[3])}};
        #pragma unroll
        for (int sgm = 0; sgm < 5; sgm++) {
          const int c = sgm * 4 + wc;
          *(ushort4*)&As[(c * 64 + r) * LDA + wkk] = seg[sgm];
        }
      }
    }
  }
  __syncthreads();

  // ---------------- phase 2: GEMM 64x128 = As(64x640) @ Wt^T ----------------
  const int lm = lane & 15, lq = lane >> 4;
  const int rs = wv & 3;         // row strip (16 rows)
  const int ch = wv >> 2;        // column half (64 cols)

  f32x4 acc[4];
  #pragma unroll
  for (int i = 0; i < 4; i++) acc[i] = (f32x4){0.f, 0.f, 0.f, 0.f};

  #pragma unroll 4
  for (int c = 0; c < 20; c++) {
    const bf16x8 a = *(const bf16x8*)&As[(c * 64 + rs * 16 + lm) * LDA + lq * 8];
    #pragma unroll
    for (int tt = 0; tt < 4; tt++) {
      const bf16x8 b = *(const bf16x8*)&Wt[(size_t)(ch * 64 + tt * 16 + lm) * K5 + c * 32 + lq * 8];
      acc[tt] = __builtin_amdgcn_mfma_f32_16x16x32_bf16(a, b, acc[tt], 0, 0, 0);
    }
  }

  // epilogue: write h + per-wave column partial sums (D: row=lq*4+rr, col=tt*16+lm)
  float psum[4], psq[4];
  #pragma unroll
  for (int tt = 0; tt < 4; tt++) {
    psum[tt] = 0.f; psq[tt] = 0.f;
    #pragma unroll
    for (int rr = 0; rr < 4; rr++) {
      const int row = m0 + rs * 16 + lq * 4 + rr;
      if (row < NNODES) {
        const float v = acc[tt][rr];
        h[(size_t)row * OUTD + ch * 64 + tt * 16 + lm] = v;
        psum[tt] += v;
        psq[tt]  += v * v;
      }
    }
  }
  #pragma unroll
  for (int tt = 0; tt < 4; tt++) {
    psum[tt] += __shfl_xor(psum[tt], 16);
    psum[tt] += __shfl_xor(psum[tt], 32);
    psq[tt]  += __shfl_xor(psq[tt], 16);
    psq[tt]  += __shfl_xor(psq[tt], 32);
  }
  if (lane < 16) {
    #pragma unroll
    for (int tt = 0; tt < 4; tt++) {
      sh_s[wv * 64 + tt * 16 + lane] = psum[tt];
      sh_q[wv * 64 + tt * 16 + lane] = psq[tt];
    }
  }
  __syncthreads();
  if (t < 128) {
    const int ch2 = t >> 6, local = t & 63;
    float ss = 0.f, qq = 0.f;
    #pragma unroll
    for (int j = 0; j < 4; j++) {
      ss += sh_s[(ch2 * 4 + j) * 64 + local];
      qq += sh_q[(ch2 * 4 + j) * 64 + local];
    }
    atomicAdd(&colsum[t], ss);
    atomicAdd(&colsumsq[t], qq);
  }
}

// ---------------- normalize + relu (in place on d_out) ----------------
__global__ void norm_k(float* __restrict__ h, const float* __restrict__ colsum,
                       const float* __restrict__ colsumsq, const float* __restrict__ gamma,
                       const float* __restrict__ beta) {
  const int i = blockIdx.x * 256 + threadIdx.x;   // float4 index
  const int total = NNODES * OUTD / 4;
  if (i >= total) return;
  const int c0 = (i * 4) & (OUTD - 1);
  const float invN = 1.0f / (float)NNODES;
  float4 v = *(const float4*)(h + (size_t)i * 4);
  float out[4] = {v.x, v.y, v.z, v.w};
  #pragma unroll
  for (int j = 0; j < 4; j++) {
    const int c = c0 + j;
    const float mu = colsum[c] * invN;
    const float var = colsumsq[c] * invN - mu * mu;
    const float rs = rsqrtf(var + EPS_BN);
    const float tv = (out[j] - mu) * rs * gamma[c] + beta[c];
    out[j] = fmaxf(tv, 0.f);
  }
  float4 o4 = {out[0], out[1], out[2], out[3]};
  *(float4*)(h + (size_t)i * 4) = o4;
}

extern "C" void kernel_launch(void* const* d_in, const int* in_sizes, int n_in,
                              void* d_out, int out_size, void* d_ws, size_t ws_size,
                              hipStream_t stream) {
  const float* inputs  = (const float*)d_in[0];
  const int*   index   = (const int*)d_in[1];
  const float* deg_emb = (const float*)d_in[2];
  const float* W       = (const float*)d_in[3];
  const float* gamma   = (const float*)d_in[4];
  const float* beta    = (const float*)d_in[5];
  const int E = in_sizes[1];

  char* ws = (char*)d_ws;
  size_t o = 0;
  int* counts = (int*)(ws + o);       o += (size_t)NNODES * 4;
  float* colsum = (float*)(ws + o);   o += 128 * 4;
  float* colsumsq = (float*)(ws + o); o += 128 * 4;
  const size_t zero_bytes = o;        // counts + colsum + colsumsq zeroed together
  o = (o + 255) & ~(size_t)255;
  int* offsets = (int*)(ws + o);      o += (size_t)NNODES * 4;
  o = (o + 255) & ~(size_t)255;
  int* cursor = (int*)(ws + o);       o += (size_t)NNODES * 4;
  o = (o + 255) & ~(size_t)255;
  int* blocksums = (int*)(ws + o);    o += 256 * 4;
  o = (o + 255) & ~(size_t)255;
  int* sorted = (int*)(ws + o);       o += (size_t)E * 4;
  o = (o + 255) & ~(size_t)255;
  unsigned short* Wt = (unsigned short*)(ws + o); o += (size_t)OUTD * K5 * 2;

  float* h = (float*)d_out;

  hipMemsetAsync(counts, 0, zero_bytes, stream);
  hist_k<<<(E + 255) / 256, 256, 0, stream>>>(index, counts, E);
  const int NB = (NNODES + 255) / 256;
  scan1_k<<<NB, 256, 0, stream>>>(counts, offsets, blocksums, NNODES);
  scan2_k<<<1, 256, 0, stream>>>(blocksums, NB);
  scan3_k<<<NB, 256, 0, stream>>>(offsets, blocksums, cursor, NNODES);
  scatter_k<<<(E + 255) / 256, 256, 0, stream>>>(index, cursor, sorted, E);
  convW_k<<<(OUTD * K5 + 255) / 256, 256, 0, stream>>>(W, Wt);
  fused_k<<<NBLK, 512, 0, stream>>>(inputs, sorted, offsets, counts, deg_emb, Wt,
                                    h, colsum, colsumsq);
  norm_k<<<(NNODES * OUTD / 4 + 255) / 256, 256, 0, stream>>>(h, colsum, colsumsq, gamma, beta);
}